// Round 10
// baseline (962.709 us; speedup 1.0000x reference)
//
#include <hip/hip_runtime.h>
#include <hip/hip_fp16.h>
#include <hip/hip_cooperative_groups.h>

namespace cg = cooperative_groups;

#define WAVE 64
#define NXCD 8
#define NRMAX 200
#define RSTRIDE 17      // float4 units: 272B row stride -> per-rel start-bank offset 4*(rel%8)
#define HOP_TPB 1024
#define HOP_BLOCKS 512
#define CAP 16          // slots per entity; P(Poisson(5)>16)~1.4e-5 -> ~3 ovf triples/run
#define OVF_CAP 32768

typedef int v4i __attribute__((ext_vector_type(4)));

// ---- fused prologue: transpose (blocks [0,tgrid)) + compute_r (next 160)
//      + cnt zeroing (rest). R17. ----
__global__ void prologue_kernel(const float* __restrict__ x, const float* __restrict__ q,
                                const float* __restrict__ W1, const float* __restrict__ b1,
                                const float* __restrict__ W2, const float* __restrict__ b2,
                                const float* __restrict__ W3, const float* __restrict__ b3,
                                float* __restrict__ rT, __half2* __restrict__ xT,
                                int* __restrict__ cnt, int N_E, int N_R, int N_W2V,
                                int tgrid, int nrx, int rblocks, int zcount) {
    __shared__ float tile[64][65];
    int bid = blockIdx.x;
    if (bid < tgrid) {
        // x (B=64, N_E) fp32 -> xT (N_E, 64) fp16. tile written [batch][entity];
        // fp16 store reads tile[2j][ei] (R3 bug was the swap).
        int e0 = bid * 64;
        int li = threadIdx.x & 63;
        int lo = threadIdx.x >> 6;
        #pragma unroll
        for (int k = 0; k < 16; ++k) {
            int b = lo + 4 * k;
            int e = e0 + li;
            tile[b][li] = (e < N_E) ? x[(size_t)b * N_E + e] : 0.0f;
        }
        __syncthreads();
        #pragma unroll
        for (int k = 0; k < 8; ++k) {
            int idx = k * 256 + threadIdx.x;     // 0..2047
            int ei  = idx >> 5;                  // entity 0..63
            int j   = idx & 31;                  // half2 col (batch pair) 0..31
            int e   = e0 + ei;
            if (e < N_E)
                xT[(size_t)e * 32 + j] = __floats2half2_rn(tile[2 * j][ei], tile[2 * j + 1][ei]);
        }
    } else if (bid < tgrid + rblocks) {
        // rT layout: [layer][N_R][64] (batch innermost, matches lane)
        int rb = bid - tgrid;
        int bx = rb % nrx;
        int by = rb / nrx;
        int lane = threadIdx.x & 63;
        int wv   = threadIdx.x >> 6;
        int b    = by * 4 + wv;
        int it   = bx * 64 + lane;
        if (it >= 3 * N_R) return;
        int l = it / N_R;
        int j = it - l * N_R;
        const float* W  = (l == 0) ? W1 : (l == 1) ? W2 : W3;
        const float* bv = (l == 0) ? b1 : (l == 1) ? b2 : b3;
        const float* qrow = q + (size_t)b * N_W2V;
        float a0 = 0.f, a1 = 0.f, a2 = 0.f, a3 = 0.f;
        int k = 0;
        for (; k + 4 <= N_W2V; k += 4) {
            a0 = fmaf(qrow[k + 0], W[(size_t)(k + 0) * N_R + j], a0);
            a1 = fmaf(qrow[k + 1], W[(size_t)(k + 1) * N_R + j], a1);
            a2 = fmaf(qrow[k + 2], W[(size_t)(k + 2) * N_R + j], a2);
            a3 = fmaf(qrow[k + 3], W[(size_t)(k + 3) * N_R + j], a3);
        }
        for (; k < N_W2V; ++k)
            a0 = fmaf(qrow[k], W[(size_t)k * N_R + j], a0);
        rT[(size_t)it * WAVE + b] = bv[j] + ((a0 + a1) + (a2 + a3));
    } else {
        // zero cnt + novf: (N_E+4) ints = zcount int4's exactly (N_E=200000)
        int zb = bid - tgrid - rblocks;
        int i4 = zb * 256 + threadIdx.x;
        if (i4 < zcount) ((v4i*)cnt)[i4] = (v4i){0, 0, 0, 0};
    }
}

// ---- helpers ----
__device__ __forceinline__ float4 h4_to_f4(uint2 v) {
    float2 f0 = __half22float2(*(__half2*)&v.x);
    float2 f1 = __half22float2(*(__half2*)&v.y);
    return make_float4(f0.x, f0.y, f1.x, f1.y);
}

__device__ __forceinline__ uint2 pack_half4(float4 a) {
    __half2 h0 = __floats2half2_rn(a.x, a.y);
    __half2 h1 = __floats2half2_rn(a.z, a.w);
    uint2 v;
    v.x = *(unsigned*)&h0;
    v.y = *(unsigned*)&h1;
    return v;
}

// 4 entities/wave, 16 lanes x uint2 (8B) per fp16 entity row.
// R18: overflow (cnt[e] > CAP, ~3 entities/run) handled INLINE: the group
// scans the tiny L2-resident ovf list for obj==e. Deletes 3 ovf dispatches.
__device__ __forceinline__ float4 hop_accum4(const uint2* __restrict__ xp,
                                             const float4* __restrict__ r_lds,
                                             const int* __restrict__ cnt,
                                             const unsigned* __restrict__ slots,
                                             const int* __restrict__ novf,
                                             const int* __restrict__ ovf_obj,
                                             const unsigned* __restrict__ ovf_pk,
                                             int e, int g, int c, int nE) {
    float4 acc = make_float4(0.f, 0.f, 0.f, 0.f);
    int lraw = (e < nE) ? cnt[e] : 0;
    int len = min(lraw, CAP);
    unsigned pv = (c < len) ? slots[(size_t)e * CAP + c] : 0u;  // whole bucket = one 64B line
    int m = max(len, __shfl_xor(len, 16));            // wave-max over the 4 groups
    m = max(m, __shfl_xor(m, 32));
    for (int j0 = 0; j0 < m; j0 += 8) {
        uint2 xv[8];
        unsigned pr[8];
        #pragma unroll
        for (int u = 0; u < 8; ++u) {                 // issue all 8 gathers first
            int jj = max(min(j0 + u, len - 1), 0);    // clamp: dup loads hit hot lines
            unsigned p = __shfl(pv, (g << 4) + jj);   // per-lane src index: group-local broadcast
            pr[u] = p >> 18;
            xv[u] = xp[(size_t)(p & 0x3FFFFu) * 16 + c];
        }
        #pragma unroll
        for (int u = 0; u < 8; ++u) {                 // consume with LDS-r FMAs
            if (j0 + u < len) {
                float4 rv = r_lds[pr[u] * RSTRIDE + c];
                float4 xf = h4_to_f4(xv[u]);
                acc.x = fmaf(xf.x, rv.x, acc.x);
                acc.y = fmaf(xf.y, rv.y, acc.y);
                acc.z = fmaf(xf.z, rv.z, acc.z);
                acc.w = fmaf(xf.w, rv.w, acc.w);
            }
        }
    }
    if (__any(lraw > CAP)) {                          // rare: inline overflow merge
        if (lraw > CAP) {
            int n = min(*novf, OVF_CAP);
            for (int i = 0; i < n; ++i) {
                if (ovf_obj[i] == e) {
                    unsigned p = ovf_pk[i];
                    float4 xf = h4_to_f4(xp[(size_t)(p & 0x3FFFFu) * 16 + c]);
                    float4 rv = r_lds[(p >> 18) * RSTRIDE + c];
                    acc.x = fmaf(xf.x, rv.x, acc.x);
                    acc.y = fmaf(xf.y, rv.y, acc.y);
                    acc.z = fmaf(xf.z, rv.z, acc.z);
                    acc.w = fmaf(xf.w, rv.w, acc.w);
                }
            }
        }
    }
    return acc;
}

__device__ __forceinline__ void stage_r(const float4* __restrict__ rT4, int nR, float4* r_lds) {
    for (int i = threadIdx.x; i < nR * 16; i += HOP_TPB)
        r_lds[(i >> 4) * RSTRIDE + (i & 15)] = rT4[i];
    __syncthreads();
}

// ---- mega kernel (R18): scatter + hop1 + hop2 + hop3(out) in ONE
// cooperative launch; grid.sync() between phases. Removes ~6 launch gaps.
// Phase structure is uniform (no early returns) so every thread reaches
// every grid.sync(). __threadfence() both sides for cross-XCD visibility.
__global__ __launch_bounds__(HOP_TPB, 8)
void mega_kernel(const int* __restrict__ subj, const int* __restrict__ rel,
                 const int* __restrict__ obj,
                 int* __restrict__ cnt, unsigned* __restrict__ slots,
                 int* __restrict__ novf, int* __restrict__ ovf_obj, unsigned* __restrict__ ovf_pk,
                 const uint2* __restrict__ X0, uint2* __restrict__ H1, uint2* __restrict__ H2,
                 const float4* __restrict__ rT4, float* __restrict__ out,
                 int nE, int nR, int nT) {
    cg::grid_group grid = cg::this_grid();
    __shared__ float4 r_lds[NRMAX * RSTRIDE];
    __shared__ float tile[64][65];

    // ---- phase 1: XCD-sharded fixed-capacity scatter (R14 form; R17's ILP
    // restructure regressed 53.7->58.3 -> reverted) ----
    {
        int grp = blockIdx.x & (NXCD - 1);
        int sh  = (nE + NXCD - 1) / NXCD;
        int lo  = grp * sh;
        int hi  = min(nE, lo + sh);
        int tid    = (blockIdx.x >> 3) * blockDim.x + threadIdx.x;
        int stride = (gridDim.x >> 3) * blockDim.x;
        int nT4 = nT >> 2;
        const v4i* obj4 = (const v4i*)obj;
        for (int t = tid; t < nT4; t += stride) {
            v4i o = obj4[t];
            int base = t * 4;
            #pragma unroll
            for (int u = 0; u < 4; ++u) {
                int oo = o[u];
                if (oo >= lo && oo < hi) {
                    unsigned pk = (unsigned)subj[base + u] | ((unsigned)rel[base + u] << 18);
                    int slot = atomicAdd(&cnt[oo], 1);
                    if (slot < CAP) slots[(size_t)oo * CAP + slot] = pk;
                    else {
                        int oi = atomicAdd(novf, 1);
                        if (oi < OVF_CAP) { ovf_obj[oi] = oo; ovf_pk[oi] = pk; }
                    }
                }
            }
        }
        for (int t = nT4 * 4 + tid; t < nT; t += stride) {
            int oo = obj[t];
            if (oo >= lo && oo < hi) {
                unsigned pk = (unsigned)subj[t] | ((unsigned)rel[t] << 18);
                int slot = atomicAdd(&cnt[oo], 1);
                if (slot < CAP) slots[(size_t)oo * CAP + slot] = pk;
                else {
                    int oi = atomicAdd(novf, 1);
                    if (oi < OVF_CAP) { ovf_obj[oi] = oo; ovf_pk[oi] = pk; }
                }
            }
        }
    }
    __threadfence();
    grid.sync();
    __threadfence();

    int lane = threadIdx.x & 63;
    int g = lane >> 4, c = lane & 15;
    int wv = threadIdx.x >> 6;                   // 0..15
    int nTiles = (nE + 63) >> 6;

    // ---- phase 2: hop1  X0 -> H1 (fp16) ----
    stage_r(rT4, nR, r_lds);
    for (int t = blockIdx.x; t < nTiles; t += gridDim.x) {
        int e = t * 64 + wv * 4 + g;
        float4 acc = hop_accum4(X0, r_lds, cnt, slots, novf, ovf_obj, ovf_pk, e, g, c, nE);
        if (e < nE) H1[(size_t)e * 16 + c] = pack_half4(acc);
    }
    __threadfence();
    grid.sync();
    __threadfence();

    // ---- phase 3: hop2  H1 -> H2 (fp16) ----
    stage_r(rT4 + (size_t)nR * 16, nR, r_lds);
    for (int t = blockIdx.x; t < nTiles; t += gridDim.x) {
        int e = t * 64 + wv * 4 + g;
        float4 acc = hop_accum4(H1, r_lds, cnt, slots, novf, ovf_obj, ovf_pk, e, g, c, nE);
        if (e < nE) H2[(size_t)e * 16 + c] = pack_half4(acc);
    }
    __threadfence();
    grid.sync();
    __threadfence();

    // ---- phase 4: hop3  H2 -> out (B, N_E) fp32, fused transpose ----
    stage_r(rT4 + (size_t)2 * nR * 16, nR, r_lds);
    for (int t = blockIdx.x; t < nTiles; t += gridDim.x) {
        int e0 = t * 64;
        int ei = wv * 4 + g;                     // 0..63 unique per (wv,g)
        float4 acc = hop_accum4(H2, r_lds, cnt, slots, novf, ovf_obj, ovf_pk, e0 + ei, g, c, nE);
        tile[ei][4 * c + 0] = acc.x;
        tile[ei][4 * c + 1] = acc.y;
        tile[ei][4 * c + 2] = acc.z;
        tile[ei][4 * c + 3] = acc.w;
        __syncthreads();
        #pragma unroll
        for (int k = 0; k < 4; ++k) {
            int b = wv * 4 + k;
            int e = e0 + lane;
            if (e < nE) out[(size_t)b * nE + e] = tile[lane][b];
        }
        __syncthreads();                         // tile reused next iteration
    }
}

extern "C" void kernel_launch(void* const* d_in, const int* in_sizes, int n_in,
                              void* d_out, int out_size, void* d_ws, size_t ws_size,
                              hipStream_t stream) {
    const float* x  = (const float*)d_in[0];
    const float* q  = (const float*)d_in[1];
    const float* W1 = (const float*)d_in[2];
    const float* b1 = (const float*)d_in[3];
    const float* W2 = (const float*)d_in[4];
    const float* b2 = (const float*)d_in[5];
    const float* W3 = (const float*)d_in[6];
    const float* b3 = (const float*)d_in[7];
    const int* subj = (const int*)d_in[8];
    const int* rel  = (const int*)d_in[9];
    const int* obj  = (const int*)d_in[10];
    // n_hop (d_in[11]) is the constant 3 per the reference; hops hardcoded.

    const int B     = 64;
    const int N_E   = in_sizes[0] / B;   // 200000
    const int N_W2V = in_sizes[1] / B;   // 300
    const int N_R   = in_sizes[3];       // 200
    const int N_T   = in_sizes[8];       // 1000000

    const size_t h16bytes = (size_t)N_E * B * sizeof(__half);   // 25.6MB per fp16 buffer

    // ws layout: [cnt nE][novf 4][ovf_obj][ovf_pk][slots nE*CAP][rT][X0 fp16][H1 fp16?]
    int*      cnt     = (int*)d_ws;
    int*      novf    = cnt + N_E;
    int*      ovf_obj = novf + 4;
    unsigned* ovf_pk  = (unsigned*)(ovf_obj + OVF_CAP);
    unsigned* slots   = ovf_pk + OVF_CAP;
    char*     rT_raw  = (char*)(slots + (size_t)N_E * CAP);
    float*    rT      = (float*)(((uintptr_t)rT_raw + 15) & ~(uintptr_t)15);
    char*     X0      = (char*)(rT + (size_t)3 * N_R * B);      // 16B-aligned
    size_t used = (size_t)(X0 - (char*)d_ws) + h16bytes;

    char* H1;
    if (ws_size >= used + h16bytes) {
        H1 = X0 + h16bytes;
        used += h16bytes;
    } else {
        H1 = (char*)d_out;   // 25.6MB scratch in the 51.2MB output; dead before hop3's write
    }
    char* H2 = X0;           // X0 dead after hop1

    // 1) fused prologue: transpose + compute_r + cnt/novf zeroing
    int tgrid   = (N_E + 63) / 64;               // 3125
    int nrx     = (3 * N_R + 63) / 64;           // 10
    int rblocks = nrx * (B / 4);                 // 160
    int zcount  = (N_E + 4) / 4;                 // 50001 int4 (N_E+4 divisible by 4)
    int zblocks = (zcount + 255) / 256;          // 196
    prologue_kernel<<<tgrid + rblocks + zblocks, 256, 0, stream>>>(
        x, q, W1, b1, W2, b2, W3, b3, rT, (__half2*)X0, cnt,
        N_E, N_R, N_W2V, tgrid, nrx, rblocks, zcount);

    // 2) mega kernel: scatter + 3 hops, one cooperative launch.
    //    Grid clamped to guaranteed co-residency, multiple of 8 (XCD shard).
    int maxb = 0;
    hipOccupancyMaxActiveBlocksPerMultiprocessor(&maxb, mega_kernel, HOP_TPB, 0);
    if (maxb < 1) maxb = 1;
    int mgrid = maxb * 256;
    if (mgrid > HOP_BLOCKS) mgrid = HOP_BLOCKS;
    mgrid &= ~7;
    if (mgrid < 8) mgrid = 8;

    const uint2*  X0u  = (const uint2*)X0;
    uint2*        H1u  = (uint2*)H1;
    uint2*        H2u  = (uint2*)H2;
    const float4* rT4p = (const float4*)rT;
    float*        outp = (float*)d_out;
    int nE_ = N_E, nR_ = N_R, nT_ = N_T;
    void* kargs[] = {
        (void*)&subj, (void*)&rel, (void*)&obj,
        (void*)&cnt, (void*)&slots, (void*)&novf, (void*)&ovf_obj, (void*)&ovf_pk,
        (void*)&X0u, (void*)&H1u, (void*)&H2u, (void*)&rT4p, (void*)&outp,
        (void*)&nE_, (void*)&nR_, (void*)&nT_
    };
    hipLaunchCooperativeKernel((void*)mega_kernel, dim3(mgrid), dim3(HOP_TPB),
                               kargs, 0, stream);
}

// Round 11
// 337.946 us; speedup vs baseline: 2.8487x; 2.8487x over previous
//
#include <hip/hip_runtime.h>
#include <hip/hip_fp16.h>

#define WAVE 64
#define NXCD 8
#define NRMAX 200
#define RSTRIDE 17      // float4 units: 272B row stride -> per-rel start-bank offset 4*(rel%8)
#define HOP_TPB 1024
#define HOP_BLOCKS 512
#define CSR_BLOCKS 2048
#define CAP 16          // slots per entity; P(Poisson(5)>16)~1.4e-5 -> ~3 ovf triples/run
#define OVF_CAP 32768

typedef int v4i __attribute__((ext_vector_type(4)));

// ---- fused front end (R19): scatter (blocks [0,2048)) + transpose
// (next tgrid) + compute_r (next 160), one dispatch. The three parts are
// independent; all feed hop1. Scatter is atomic-latency-bound (1.9TB/s,
// VALU 5%) and overlaps the BW-bound transpose on complementary resources.
// R10 lesson: cooperative grid.sync fusion flushes non-coherent XCD L2s
// (402GB/s, 4x slower) -- fuse only independent work, sync via dispatch.
__global__ void fused_front_kernel(const float* __restrict__ x, const float* __restrict__ q,
                                   const float* __restrict__ W1, const float* __restrict__ b1,
                                   const float* __restrict__ W2, const float* __restrict__ b2,
                                   const float* __restrict__ W3, const float* __restrict__ b3,
                                   const int* __restrict__ subj, const int* __restrict__ rel,
                                   const int* __restrict__ obj,
                                   int* __restrict__ cnt, unsigned* __restrict__ slots,
                                   int* __restrict__ novf, int* __restrict__ ovf_obj,
                                   unsigned* __restrict__ ovf_pk,
                                   float* __restrict__ rT, __half2* __restrict__ xT,
                                   int N_E, int N_R, int N_W2V, int nT,
                                   int tgrid, int nrx) {
    __shared__ float tile[64][65];
    int bid = blockIdx.x;
    if (bid < CSR_BLOCKS) {
        // ---- XCD-sharded fixed-capacity scatter (R14 form; R17 ILP regressed) ----
        int grp = bid & (NXCD - 1);
        int sh  = (N_E + NXCD - 1) / NXCD;
        int lo  = grp * sh;
        int hi  = min(N_E, lo + sh);
        int tid    = (bid >> 3) * blockDim.x + threadIdx.x;
        int stride = (CSR_BLOCKS >> 3) * blockDim.x;     // NOT gridDim.x: grid is larger
        int nT4 = nT >> 2;
        const v4i* obj4 = (const v4i*)obj;
        for (int t = tid; t < nT4; t += stride) {
            v4i o = obj4[t];
            int base = t * 4;
            #pragma unroll
            for (int u = 0; u < 4; ++u) {
                int oo = o[u];
                if (oo >= lo && oo < hi) {
                    unsigned pk = (unsigned)subj[base + u] | ((unsigned)rel[base + u] << 18);
                    int slot = atomicAdd(&cnt[oo], 1);
                    if (slot < CAP) slots[(size_t)oo * CAP + slot] = pk;
                    else {
                        int oi = atomicAdd(novf, 1);
                        if (oi < OVF_CAP) { ovf_obj[oi] = oo; ovf_pk[oi] = pk; }
                    }
                }
            }
        }
        for (int t = nT4 * 4 + tid; t < nT; t += stride) {
            int oo = obj[t];
            if (oo >= lo && oo < hi) {
                unsigned pk = (unsigned)subj[t] | ((unsigned)rel[t] << 18);
                int slot = atomicAdd(&cnt[oo], 1);
                if (slot < CAP) slots[(size_t)oo * CAP + slot] = pk;
                else {
                    int oi = atomicAdd(novf, 1);
                    if (oi < OVF_CAP) { ovf_obj[oi] = oo; ovf_pk[oi] = pk; }
                }
            }
        }
    } else if (bid < CSR_BLOCKS + tgrid) {
        // ---- x (B=64, N_E) fp32 -> xT (N_E, 64) fp16. tile written
        // [batch][entity]; fp16 store reads tile[2j][ei] (R3 bug was the swap). ----
        int e0 = (bid - CSR_BLOCKS) * 64;
        int li = threadIdx.x & 63;
        int lo = threadIdx.x >> 6;
        #pragma unroll
        for (int k = 0; k < 16; ++k) {
            int b = lo + 4 * k;
            int e = e0 + li;
            tile[b][li] = (e < N_E) ? x[(size_t)b * N_E + e] : 0.0f;
        }
        __syncthreads();
        #pragma unroll
        for (int k = 0; k < 8; ++k) {
            int idx = k * 256 + threadIdx.x;     // 0..2047
            int ei  = idx >> 5;                  // entity 0..63
            int j   = idx & 31;                  // half2 col (batch pair) 0..31
            int e   = e0 + ei;
            if (e < N_E)
                xT[(size_t)e * 32 + j] = __floats2half2_rn(tile[2 * j][ei], tile[2 * j + 1][ei]);
        }
    } else {
        // ---- rT layout: [layer][N_R][64] (batch innermost, matches lane) ----
        int rb = bid - CSR_BLOCKS - tgrid;
        int bx = rb % nrx;
        int by = rb / nrx;
        int lane = threadIdx.x & 63;
        int wv   = threadIdx.x >> 6;
        int b    = by * 4 + wv;
        int it   = bx * 64 + lane;
        if (it >= 3 * N_R) return;
        int l = it / N_R;
        int j = it - l * N_R;
        const float* W  = (l == 0) ? W1 : (l == 1) ? W2 : W3;
        const float* bv = (l == 0) ? b1 : (l == 1) ? b2 : b3;
        const float* qrow = q + (size_t)b * N_W2V;
        float a0 = 0.f, a1 = 0.f, a2 = 0.f, a3 = 0.f;
        int k = 0;
        for (; k + 4 <= N_W2V; k += 4) {
            a0 = fmaf(qrow[k + 0], W[(size_t)(k + 0) * N_R + j], a0);
            a1 = fmaf(qrow[k + 1], W[(size_t)(k + 1) * N_R + j], a1);
            a2 = fmaf(qrow[k + 2], W[(size_t)(k + 2) * N_R + j], a2);
            a3 = fmaf(qrow[k + 3], W[(size_t)(k + 3) * N_R + j], a3);
        }
        for (; k < N_W2V; ++k)
            a0 = fmaf(qrow[k], W[(size_t)k * N_R + j], a0);
        rT[(size_t)it * WAVE + b] = bv[j] + ((a0 + a1) + (a2 + a3));
    }
}

// ---- hops ----
// R10: fp16 intermediates. R12: fp16 x0 + unroll-8 issue-early gathers.
// R13: gather FETCH matches the distinct-line floor -> random-access-BW
// bound (~3.5TB/s). R18 (kept from mega): overflow merged INLINE -- the
// group computing entity e scans the tiny L2-resident ovf list; same-block
// compute, no cross-phase coherence needed. Deletes 3 ovf dispatches.

__device__ __forceinline__ float4 h4_to_f4(uint2 v) {
    float2 f0 = __half22float2(*(__half2*)&v.x);
    float2 f1 = __half22float2(*(__half2*)&v.y);
    return make_float4(f0.x, f0.y, f1.x, f1.y);
}

__device__ __forceinline__ uint2 pack_half4(float4 a) {
    __half2 h0 = __floats2half2_rn(a.x, a.y);
    __half2 h1 = __floats2half2_rn(a.z, a.w);
    uint2 v;
    v.x = *(unsigned*)&h0;
    v.y = *(unsigned*)&h1;
    return v;
}

// 4 entities/wave, 16 lanes x uint2 (8B) per fp16 entity row.
__device__ __forceinline__ float4 hop_accum4(const uint2* __restrict__ xp,
                                             const float4* __restrict__ r_lds,
                                             const int* __restrict__ cnt,
                                             const unsigned* __restrict__ slots,
                                             const int* __restrict__ novf,
                                             const int* __restrict__ ovf_obj,
                                             const unsigned* __restrict__ ovf_pk,
                                             int e, int g, int c, int nE) {
    float4 acc = make_float4(0.f, 0.f, 0.f, 0.f);
    int lraw = (e < nE) ? cnt[e] : 0;
    int len = min(lraw, CAP);
    unsigned pv = (c < len) ? slots[(size_t)e * CAP + c] : 0u;  // whole bucket = one 64B line
    int m = max(len, __shfl_xor(len, 16));            // wave-max over the 4 groups
    m = max(m, __shfl_xor(m, 32));
    for (int j0 = 0; j0 < m; j0 += 8) {
        uint2 xv[8];
        unsigned pr[8];
        #pragma unroll
        for (int u = 0; u < 8; ++u) {                 // issue all 8 gathers first
            int jj = max(min(j0 + u, len - 1), 0);    // clamp: dup loads hit hot lines
            unsigned p = __shfl(pv, (g << 4) + jj);   // per-lane src index: group-local broadcast
            pr[u] = p >> 18;
            xv[u] = xp[(size_t)(p & 0x3FFFFu) * 16 + c];
        }
        #pragma unroll
        for (int u = 0; u < 8; ++u) {                 // consume with LDS-r FMAs
            if (j0 + u < len) {
                float4 rv = r_lds[pr[u] * RSTRIDE + c];
                float4 xf = h4_to_f4(xv[u]);
                acc.x = fmaf(xf.x, rv.x, acc.x);
                acc.y = fmaf(xf.y, rv.y, acc.y);
                acc.z = fmaf(xf.z, rv.z, acc.z);
                acc.w = fmaf(xf.w, rv.w, acc.w);
            }
        }
    }
    if (__any(lraw > CAP)) {                          // rare (~3 entities/run)
        if (lraw > CAP) {
            int n = min(*novf, OVF_CAP);
            for (int i = 0; i < n; ++i) {
                if (ovf_obj[i] == e) {
                    unsigned p = ovf_pk[i];
                    float4 xf = h4_to_f4(xp[(size_t)(p & 0x3FFFFu) * 16 + c]);
                    float4 rv = r_lds[(p >> 18) * RSTRIDE + c];
                    acc.x = fmaf(xf.x, rv.x, acc.x);
                    acc.y = fmaf(xf.y, rv.y, acc.y);
                    acc.z = fmaf(xf.z, rv.z, acc.z);
                    acc.w = fmaf(xf.w, rv.w, acc.w);
                }
            }
        }
    }
    return acc;
}

// hops 1-2: 1024-thread blocks (16 waves x 4 entities = 64-entity tiles),
// grid-stride, 512 resident blocks (2/CU, 32 waves/CU). fp16 in, fp16 out.
__global__ __launch_bounds__(HOP_TPB, 8)
void hop_mid_kernel(const uint2* __restrict__ xp, const float4* __restrict__ rT4,
                    const int* __restrict__ cnt, const unsigned* __restrict__ slots,
                    const int* __restrict__ novf, const int* __restrict__ ovf_obj,
                    const unsigned* __restrict__ ovf_pk,
                    uint2* __restrict__ yh, int nE, int nR) {
    __shared__ float4 r_lds[NRMAX * RSTRIDE];
    for (int i = threadIdx.x; i < nR * 16; i += HOP_TPB)
        r_lds[(i >> 4) * RSTRIDE + (i & 15)] = rT4[i];
    __syncthreads();
    int lane = threadIdx.x & 63;
    int g = lane >> 4, c = lane & 15;
    int wv = threadIdx.x >> 6;                   // 0..15
    int nTiles = (nE + 63) >> 6;
    for (int t = blockIdx.x; t < nTiles; t += gridDim.x) {
        int e = t * 64 + wv * 4 + g;
        float4 acc = hop_accum4(xp, r_lds, cnt, slots, novf, ovf_obj, ovf_pk, e, g, c, nE);
        if (e < nE) yh[(size_t)e * 16 + c] = pack_half4(acc);
    }
}

// hop 3 fused with output transpose: 64-entity LDS tile, stores (B, N_E) fp32.
__global__ __launch_bounds__(HOP_TPB, 8)
void hop_out_kernel(const uint2* __restrict__ xp, const float4* __restrict__ rT4,
                    const int* __restrict__ cnt, const unsigned* __restrict__ slots,
                    const int* __restrict__ novf, const int* __restrict__ ovf_obj,
                    const unsigned* __restrict__ ovf_pk,
                    float* __restrict__ out, int nE, int nR) {
    __shared__ float4 r_lds[NRMAX * RSTRIDE];
    __shared__ float tile[64][65];
    for (int i = threadIdx.x; i < nR * 16; i += HOP_TPB)
        r_lds[(i >> 4) * RSTRIDE + (i & 15)] = rT4[i];
    __syncthreads();
    int lane = threadIdx.x & 63;
    int g = lane >> 4, c = lane & 15;
    int wv = threadIdx.x >> 6;                   // 0..15
    int nTiles = (nE + 63) >> 6;
    for (int t = blockIdx.x; t < nTiles; t += gridDim.x) {
        int e0 = t * 64;
        int ei = wv * 4 + g;                     // 0..63 unique per (wv,g)
        float4 acc = hop_accum4(xp, r_lds, cnt, slots, novf, ovf_obj, ovf_pk, e0 + ei, g, c, nE);
        tile[ei][4 * c + 0] = acc.x;
        tile[ei][4 * c + 1] = acc.y;
        tile[ei][4 * c + 2] = acc.z;
        tile[ei][4 * c + 3] = acc.w;
        __syncthreads();
        #pragma unroll
        for (int k = 0; k < 4; ++k) {
            int b = wv * 4 + k;
            int e = e0 + lane;
            if (e < nE) out[(size_t)b * nE + e] = tile[lane][b];
        }
        __syncthreads();                         // tile reused next iteration
    }
}

extern "C" void kernel_launch(void* const* d_in, const int* in_sizes, int n_in,
                              void* d_out, int out_size, void* d_ws, size_t ws_size,
                              hipStream_t stream) {
    const float* x  = (const float*)d_in[0];
    const float* q  = (const float*)d_in[1];
    const float* W1 = (const float*)d_in[2];
    const float* b1 = (const float*)d_in[3];
    const float* W2 = (const float*)d_in[4];
    const float* b2 = (const float*)d_in[5];
    const float* W3 = (const float*)d_in[6];
    const float* b3 = (const float*)d_in[7];
    const int* subj = (const int*)d_in[8];
    const int* rel  = (const int*)d_in[9];
    const int* obj  = (const int*)d_in[10];
    // n_hop (d_in[11]) is the constant 3 per the reference; hops hardcoded.

    const int B     = 64;
    const int N_E   = in_sizes[0] / B;   // 200000
    const int N_W2V = in_sizes[1] / B;   // 300
    const int N_R   = in_sizes[3];       // 200
    const int N_T   = in_sizes[8];       // 1000000

    const size_t h16bytes = (size_t)N_E * B * sizeof(__half);   // 25.6MB per fp16 buffer

    // ws layout: [cnt nE][novf 4][ovf_obj][ovf_pk][slots nE*CAP][rT][X0 fp16][H1 fp16?]
    int*      cnt     = (int*)d_ws;
    int*      novf    = cnt + N_E;
    int*      ovf_obj = novf + 4;
    unsigned* ovf_pk  = (unsigned*)(ovf_obj + OVF_CAP);
    unsigned* slots   = ovf_pk + OVF_CAP;
    char*     rT_raw  = (char*)(slots + (size_t)N_E * CAP);
    float*    rT      = (float*)(((uintptr_t)rT_raw + 15) & ~(uintptr_t)15);
    char*     X0      = (char*)(rT + (size_t)3 * N_R * B);      // 16B-aligned
    size_t used = (size_t)(X0 - (char*)d_ws) + h16bytes;

    char* H1;
    if (ws_size >= used + h16bytes) {
        H1 = X0 + h16bytes;
        used += h16bytes;
    } else {
        H1 = (char*)d_out;   // 25.6MB scratch in the 51.2MB output; dead before hop3's write
    }
    char* H2 = X0;           // X0 dead after hop1

    // 1) zero cnt + novf, then fused front end (scatter | transpose | compute_r)
    hipMemsetAsync(cnt, 0, (size_t)(N_E + 4) * sizeof(int), stream);
    int tgrid = (N_E + 63) / 64;                 // 3125
    int nrx   = (3 * N_R + 63) / 64;             // 10
    int rblocks = nrx * (B / 4);                 // 160
    fused_front_kernel<<<CSR_BLOCKS + tgrid + rblocks, 256, 0, stream>>>(
        x, q, W1, b1, W2, b2, W3, b3, subj, rel, obj,
        cnt, slots, novf, ovf_obj, ovf_pk, rT, (__half2*)X0,
        N_E, N_R, N_W2V, N_T, tgrid, nrx);

    // 2) three hops (overflow merged inline); hop3 fuses the output transpose
    int hblocks = tgrid < HOP_BLOCKS ? tgrid : HOP_BLOCKS;
    const float4* rT1 = (const float4*)rT;
    const float4* rT2 = (const float4*)(rT + (size_t)1 * N_R * B);
    const float4* rT3 = (const float4*)(rT + (size_t)2 * N_R * B);

    hop_mid_kernel<<<hblocks, HOP_TPB, 0, stream>>>(
        (const uint2*)X0, rT1, cnt, slots, novf, ovf_obj, ovf_pk, (uint2*)H1, N_E, N_R);
    hop_mid_kernel<<<hblocks, HOP_TPB, 0, stream>>>(
        (const uint2*)H1, rT2, cnt, slots, novf, ovf_obj, ovf_pk, (uint2*)H2, N_E, N_R);
    hop_out_kernel<<<hblocks, HOP_TPB, 0, stream>>>(
        (const uint2*)H2, rT3, cnt, slots, novf, ovf_obj, ovf_pk, (float*)d_out, N_E, N_R);
}

// Round 12
// 326.913 us; speedup vs baseline: 2.9448x; 1.0337x over previous
//
#include <hip/hip_runtime.h>
#include <hip/hip_fp16.h>

#define WAVE 64
#define NXCD 8
#define NRMAX 200
#define RSTRIDE 17      // float4 units: 272B row stride -> per-rel start-bank offset 4*(rel%8)
#define HOP_TPB 1024
#define HOP_BLOCKS 512
#define CSR_BLOCKS 2048
#define CSR_TPB 256
#define CAP 16          // slots per entity; P(Poisson(5)>16)~1.4e-5 -> ~3 ovf triples/run
#define OVF_CAP 32768

typedef int v4i __attribute__((ext_vector_type(4)));

// ---- prologue (R9 form, verified): transpose (blocks [0,tgrid)) +
// compute_r (next 160) + cnt/novf zeroing (rest). One dispatch.
// R11 lesson: do NOT fuse the scatter in here -- the 51MB x-stream +
// 25.6MB xT-store thrash the per-XCD L2s the scatter needs for slots/cnt
// residency (+27us interference vs ~6.5us boundary cost). ----
__global__ void prologue_kernel(const float* __restrict__ x, const float* __restrict__ q,
                                const float* __restrict__ W1, const float* __restrict__ b1,
                                const float* __restrict__ W2, const float* __restrict__ b2,
                                const float* __restrict__ W3, const float* __restrict__ b3,
                                float* __restrict__ rT, __half2* __restrict__ xT,
                                int* __restrict__ cnt, int N_E, int N_R, int N_W2V,
                                int tgrid, int nrx, int rblocks, int zcount) {
    __shared__ float tile[64][65];
    int bid = blockIdx.x;
    if (bid < tgrid) {
        // x (B=64, N_E) fp32 -> xT (N_E, 64) fp16. tile written [batch][entity];
        // fp16 store reads tile[2j][ei] (R3 bug was the swap).
        int e0 = bid * 64;
        int li = threadIdx.x & 63;
        int lo = threadIdx.x >> 6;
        #pragma unroll
        for (int k = 0; k < 16; ++k) {
            int b = lo + 4 * k;
            int e = e0 + li;
            tile[b][li] = (e < N_E) ? x[(size_t)b * N_E + e] : 0.0f;
        }
        __syncthreads();
        #pragma unroll
        for (int k = 0; k < 8; ++k) {
            int idx = k * 256 + threadIdx.x;     // 0..2047
            int ei  = idx >> 5;                  // entity 0..63
            int j   = idx & 31;                  // half2 col (batch pair) 0..31
            int e   = e0 + ei;
            if (e < N_E)
                xT[(size_t)e * 32 + j] = __floats2half2_rn(tile[2 * j][ei], tile[2 * j + 1][ei]);
        }
    } else if (bid < tgrid + rblocks) {
        // rT layout: [layer][N_R][64] (batch innermost, matches lane)
        int rb = bid - tgrid;
        int bx = rb % nrx;
        int by = rb / nrx;
        int lane = threadIdx.x & 63;
        int wv   = threadIdx.x >> 6;
        int b    = by * 4 + wv;
        int it   = bx * 64 + lane;
        if (it >= 3 * N_R) return;
        int l = it / N_R;
        int j = it - l * N_R;
        const float* W  = (l == 0) ? W1 : (l == 1) ? W2 : W3;
        const float* bv = (l == 0) ? b1 : (l == 1) ? b2 : b3;
        const float* qrow = q + (size_t)b * N_W2V;
        float a0 = 0.f, a1 = 0.f, a2 = 0.f, a3 = 0.f;
        int k = 0;
        for (; k + 4 <= N_W2V; k += 4) {
            a0 = fmaf(qrow[k + 0], W[(size_t)(k + 0) * N_R + j], a0);
            a1 = fmaf(qrow[k + 1], W[(size_t)(k + 1) * N_R + j], a1);
            a2 = fmaf(qrow[k + 2], W[(size_t)(k + 2) * N_R + j], a2);
            a3 = fmaf(qrow[k + 3], W[(size_t)(k + 3) * N_R + j], a3);
        }
        for (; k < N_W2V; ++k)
            a0 = fmaf(qrow[k], W[(size_t)k * N_R + j], a0);
        rT[(size_t)it * WAVE + b] = bv[j] + ((a0 + a1) + (a2 + a3));
    } else {
        // zero cnt + novf: (N_E+4) ints = zcount int4's exactly (N_E=200000)
        int zb = bid - tgrid - rblocks;
        int i4 = zb * 256 + threadIdx.x;
        if (i4 < zcount) ((v4i*)cnt)[i4] = (v4i){0, 0, 0, 0};
    }
}

// ---- bucket build (R14/R6 exact form, measured 53.7us standalone) ----
// R5: XCD group only touches its own entity slice. One fixed-capacity
// atomic pass; ~50us is the device floor for 1M random device-scope
// atomics (R16/R17: three structures all 42-58us; ILP restructure and
// partition both regressed).
__global__ void scatter_direct_kernel(const int* __restrict__ subj, const int* __restrict__ rel,
                                      const int* __restrict__ obj,
                                      int* __restrict__ cnt, unsigned* __restrict__ slots,
                                      int* __restrict__ novf, int* __restrict__ ovf_obj,
                                      unsigned* __restrict__ ovf_pk, int nT, int nE) {
    int grp = blockIdx.x & (NXCD - 1);
    int sh  = (nE + NXCD - 1) / NXCD;
    int lo  = grp * sh;
    int hi  = min(nE, lo + sh);
    int tid    = (blockIdx.x >> 3) * blockDim.x + threadIdx.x;
    int stride = (gridDim.x >> 3) * blockDim.x;
    int nT4 = nT >> 2;
    const v4i* obj4 = (const v4i*)obj;
    for (int t = tid; t < nT4; t += stride) {
        v4i o = obj4[t];
        int base = t * 4;
        #pragma unroll
        for (int u = 0; u < 4; ++u) {
            int oo = o[u];
            if (oo >= lo && oo < hi) {
                unsigned pk = (unsigned)subj[base + u] | ((unsigned)rel[base + u] << 18);
                int slot = atomicAdd(&cnt[oo], 1);
                if (slot < CAP) slots[(size_t)oo * CAP + slot] = pk;
                else {
                    int oi = atomicAdd(novf, 1);
                    if (oi < OVF_CAP) { ovf_obj[oi] = oo; ovf_pk[oi] = pk; }
                }
            }
        }
    }
    for (int t = nT4 * 4 + tid; t < nT; t += stride) {
        int oo = obj[t];
        if (oo >= lo && oo < hi) {
            unsigned pk = (unsigned)subj[t] | ((unsigned)rel[t] << 18);
            int slot = atomicAdd(&cnt[oo], 1);
            if (slot < CAP) slots[(size_t)oo * CAP + slot] = pk;
            else {
                int oi = atomicAdd(novf, 1);
                if (oi < OVF_CAP) { ovf_obj[oi] = oo; ovf_pk[oi] = pk; }
            }
        }
    }
}

// ---- hops ----
// R10: fp16 intermediates. R12: fp16 x0 + unroll-8 issue-early gathers.
// R13: gather FETCH matches the distinct-line floor -> random-access-BW
// bound (~3.5TB/s). R18: overflow merged INLINE (same-block compute, no
// cross-phase coherence); deleted 3 ovf dispatches.

__device__ __forceinline__ float4 h4_to_f4(uint2 v) {
    float2 f0 = __half22float2(*(__half2*)&v.x);
    float2 f1 = __half22float2(*(__half2*)&v.y);
    return make_float4(f0.x, f0.y, f1.x, f1.y);
}

__device__ __forceinline__ uint2 pack_half4(float4 a) {
    __half2 h0 = __floats2half2_rn(a.x, a.y);
    __half2 h1 = __floats2half2_rn(a.z, a.w);
    uint2 v;
    v.x = *(unsigned*)&h0;
    v.y = *(unsigned*)&h1;
    return v;
}

// 4 entities/wave, 16 lanes x uint2 (8B) per fp16 entity row.
__device__ __forceinline__ float4 hop_accum4(const uint2* __restrict__ xp,
                                             const float4* __restrict__ r_lds,
                                             const int* __restrict__ cnt,
                                             const unsigned* __restrict__ slots,
                                             const int* __restrict__ novf,
                                             const int* __restrict__ ovf_obj,
                                             const unsigned* __restrict__ ovf_pk,
                                             int e, int g, int c, int nE) {
    float4 acc = make_float4(0.f, 0.f, 0.f, 0.f);
    int lraw = (e < nE) ? cnt[e] : 0;
    int len = min(lraw, CAP);
    unsigned pv = (c < len) ? slots[(size_t)e * CAP + c] : 0u;  // whole bucket = one 64B line
    int m = max(len, __shfl_xor(len, 16));            // wave-max over the 4 groups
    m = max(m, __shfl_xor(m, 32));
    for (int j0 = 0; j0 < m; j0 += 8) {
        uint2 xv[8];
        unsigned pr[8];
        #pragma unroll
        for (int u = 0; u < 8; ++u) {                 // issue all 8 gathers first
            int jj = max(min(j0 + u, len - 1), 0);    // clamp: dup loads hit hot lines
            unsigned p = __shfl(pv, (g << 4) + jj);   // per-lane src index: group-local broadcast
            pr[u] = p >> 18;
            xv[u] = xp[(size_t)(p & 0x3FFFFu) * 16 + c];
        }
        #pragma unroll
        for (int u = 0; u < 8; ++u) {                 // consume with LDS-r FMAs
            if (j0 + u < len) {
                float4 rv = r_lds[pr[u] * RSTRIDE + c];
                float4 xf = h4_to_f4(xv[u]);
                acc.x = fmaf(xf.x, rv.x, acc.x);
                acc.y = fmaf(xf.y, rv.y, acc.y);
                acc.z = fmaf(xf.z, rv.z, acc.z);
                acc.w = fmaf(xf.w, rv.w, acc.w);
            }
        }
    }
    if (__any(lraw > CAP)) {                          // rare (~3 entities/run)
        if (lraw > CAP) {
            int n = min(*novf, OVF_CAP);
            for (int i = 0; i < n; ++i) {
                if (ovf_obj[i] == e) {
                    unsigned p = ovf_pk[i];
                    float4 xf = h4_to_f4(xp[(size_t)(p & 0x3FFFFu) * 16 + c]);
                    float4 rv = r_lds[(p >> 18) * RSTRIDE + c];
                    acc.x = fmaf(xf.x, rv.x, acc.x);
                    acc.y = fmaf(xf.y, rv.y, acc.y);
                    acc.z = fmaf(xf.z, rv.z, acc.z);
                    acc.w = fmaf(xf.w, rv.w, acc.w);
                }
            }
        }
    }
    return acc;
}

// hops 1-2: 1024-thread blocks (16 waves x 4 entities = 64-entity tiles),
// grid-stride, 512 resident blocks (2/CU, 32 waves/CU). fp16 in, fp16 out.
__global__ __launch_bounds__(HOP_TPB, 8)
void hop_mid_kernel(const uint2* __restrict__ xp, const float4* __restrict__ rT4,
                    const int* __restrict__ cnt, const unsigned* __restrict__ slots,
                    const int* __restrict__ novf, const int* __restrict__ ovf_obj,
                    const unsigned* __restrict__ ovf_pk,
                    uint2* __restrict__ yh, int nE, int nR) {
    __shared__ float4 r_lds[NRMAX * RSTRIDE];
    for (int i = threadIdx.x; i < nR * 16; i += HOP_TPB)
        r_lds[(i >> 4) * RSTRIDE + (i & 15)] = rT4[i];
    __syncthreads();
    int lane = threadIdx.x & 63;
    int g = lane >> 4, c = lane & 15;
    int wv = threadIdx.x >> 6;                   // 0..15
    int nTiles = (nE + 63) >> 6;
    for (int t = blockIdx.x; t < nTiles; t += gridDim.x) {
        int e = t * 64 + wv * 4 + g;
        float4 acc = hop_accum4(xp, r_lds, cnt, slots, novf, ovf_obj, ovf_pk, e, g, c, nE);
        if (e < nE) yh[(size_t)e * 16 + c] = pack_half4(acc);
    }
}

// hop 3 fused with output transpose: 64-entity LDS tile, stores (B, N_E) fp32.
__global__ __launch_bounds__(HOP_TPB, 8)
void hop_out_kernel(const uint2* __restrict__ xp, const float4* __restrict__ rT4,
                    const int* __restrict__ cnt, const unsigned* __restrict__ slots,
                    const int* __restrict__ novf, const int* __restrict__ ovf_obj,
                    const unsigned* __restrict__ ovf_pk,
                    float* __restrict__ out, int nE, int nR) {
    __shared__ float4 r_lds[NRMAX * RSTRIDE];
    __shared__ float tile[64][65];
    for (int i = threadIdx.x; i < nR * 16; i += HOP_TPB)
        r_lds[(i >> 4) * RSTRIDE + (i & 15)] = rT4[i];
    __syncthreads();
    int lane = threadIdx.x & 63;
    int g = lane >> 4, c = lane & 15;
    int wv = threadIdx.x >> 6;                   // 0..15
    int nTiles = (nE + 63) >> 6;
    for (int t = blockIdx.x; t < nTiles; t += gridDim.x) {
        int e0 = t * 64;
        int ei = wv * 4 + g;                     // 0..63 unique per (wv,g)
        float4 acc = hop_accum4(xp, r_lds, cnt, slots, novf, ovf_obj, ovf_pk, e0 + ei, g, c, nE);
        tile[ei][4 * c + 0] = acc.x;
        tile[ei][4 * c + 1] = acc.y;
        tile[ei][4 * c + 2] = acc.z;
        tile[ei][4 * c + 3] = acc.w;
        __syncthreads();
        #pragma unroll
        for (int k = 0; k < 4; ++k) {
            int b = wv * 4 + k;
            int e = e0 + lane;
            if (e < nE) out[(size_t)b * nE + e] = tile[lane][b];
        }
        __syncthreads();                         // tile reused next iteration
    }
}

extern "C" void kernel_launch(void* const* d_in, const int* in_sizes, int n_in,
                              void* d_out, int out_size, void* d_ws, size_t ws_size,
                              hipStream_t stream) {
    const float* x  = (const float*)d_in[0];
    const float* q  = (const float*)d_in[1];
    const float* W1 = (const float*)d_in[2];
    const float* b1 = (const float*)d_in[3];
    const float* W2 = (const float*)d_in[4];
    const float* b2 = (const float*)d_in[5];
    const float* W3 = (const float*)d_in[6];
    const float* b3 = (const float*)d_in[7];
    const int* subj = (const int*)d_in[8];
    const int* rel  = (const int*)d_in[9];
    const int* obj  = (const int*)d_in[10];
    // n_hop (d_in[11]) is the constant 3 per the reference; hops hardcoded.

    const int B     = 64;
    const int N_E   = in_sizes[0] / B;   // 200000
    const int N_W2V = in_sizes[1] / B;   // 300
    const int N_R   = in_sizes[3];       // 200
    const int N_T   = in_sizes[8];       // 1000000

    const size_t h16bytes = (size_t)N_E * B * sizeof(__half);   // 25.6MB per fp16 buffer

    // ws layout: [cnt nE][novf 4][ovf_obj][ovf_pk][slots nE*CAP][rT][X0 fp16][H1 fp16?]
    int*      cnt     = (int*)d_ws;
    int*      novf    = cnt + N_E;
    int*      ovf_obj = novf + 4;
    unsigned* ovf_pk  = (unsigned*)(ovf_obj + OVF_CAP);
    unsigned* slots   = ovf_pk + OVF_CAP;
    char*     rT_raw  = (char*)(slots + (size_t)N_E * CAP);
    float*    rT      = (float*)(((uintptr_t)rT_raw + 15) & ~(uintptr_t)15);
    char*     X0      = (char*)(rT + (size_t)3 * N_R * B);      // 16B-aligned
    size_t used = (size_t)(X0 - (char*)d_ws) + h16bytes;

    char* H1;
    if (ws_size >= used + h16bytes) {
        H1 = X0 + h16bytes;
        used += h16bytes;
    } else {
        H1 = (char*)d_out;   // 25.6MB scratch in the 51.2MB output; dead before hop3's write
    }
    char* H2 = X0;           // X0 dead after hop1

    // 1) prologue: transpose + compute_r + cnt/novf zeroing (one dispatch)
    int tgrid   = (N_E + 63) / 64;               // 3125
    int nrx     = (3 * N_R + 63) / 64;           // 10
    int rblocks = nrx * (B / 4);                 // 160
    int zcount  = (N_E + 4) / 4;                 // 50001 int4 (N_E+4 divisible by 4)
    int zblocks = (zcount + 255) / 256;          // 196
    prologue_kernel<<<tgrid + rblocks + zblocks, 256, 0, stream>>>(
        x, q, W1, b1, W2, b2, W3, b3, rT, (__half2*)X0, cnt,
        N_E, N_R, N_W2V, tgrid, nrx, rblocks, zcount);

    // 2) bucket build: one XCD-sharded atomic pass (standalone: no L2
    //    interference from the transpose stream)
    scatter_direct_kernel<<<CSR_BLOCKS, CSR_TPB, 0, stream>>>(
        subj, rel, obj, cnt, slots, novf, ovf_obj, ovf_pk, N_T, N_E);

    // 3) three hops (overflow merged inline); hop3 fuses the output transpose
    int hblocks = tgrid < HOP_BLOCKS ? tgrid : HOP_BLOCKS;
    const float4* rT1 = (const float4*)rT;
    const float4* rT2 = (const float4*)(rT + (size_t)1 * N_R * B);
    const float4* rT3 = (const float4*)(rT + (size_t)2 * N_R * B);

    hop_mid_kernel<<<hblocks, HOP_TPB, 0, stream>>>(
        (const uint2*)X0, rT1, cnt, slots, novf, ovf_obj, ovf_pk, (uint2*)H1, N_E, N_R);
    hop_mid_kernel<<<hblocks, HOP_TPB, 0, stream>>>(
        (const uint2*)H1, rT2, cnt, slots, novf, ovf_obj, ovf_pk, (uint2*)H2, N_E, N_R);
    hop_out_kernel<<<hblocks, HOP_TPB, 0, stream>>>(
        (const uint2*)H2, rT3, cnt, slots, novf, ovf_obj, ovf_pk, (float*)d_out, N_E, N_R);
}